// Round 13
// baseline (576.271 us; speedup 1.0000x reference)
//
#include <hip/hip_runtime.h>
#include <stdint.h>

// DenseGGNN on MI355X, round 13.
//  - Algebra swap: m = A^T(hW) = (A^T h) W. k_mega8 per layer does:
//    phase 1  : q = adjT @ hT (R9 k_mega6 phase-1 verbatim, B=hT instead of hwT)
//    phase 1.5: m = q @ W (q split hi/lo in LDS -> MFMA 3-product vs wT, b-frags global)
//    phase 2  : gates + GRU (R9 verbatim)
//    epilogue : h row-major in-place (own rows) + hT via bounce transpose (k_hw2 pattern)
//  - hT double-buffered across layers (phase-1 readers see prev-dispatch data only).
//  - k_hw eliminated; 5 dispatches total (was 9; ~11 us/gap measured).
//  - Cooperative launch (R12) failed at launch -> abandoned.

#define NB 32
#define NN 1024
#define NC 128
#define NL 4
#define MTOT (NB * NN)   // 32768

#define MP 136           // q/m LDS pitch (U16): row stride 272B -> bank step 4, <=2-way

typedef __attribute__((ext_vector_type(8))) short s16x8;
typedef __attribute__((ext_vector_type(4))) float f32x4;
typedef __attribute__((ext_vector_type(2))) unsigned int u32x2;
typedef unsigned short U16;
typedef unsigned int U32;

__device__ __forceinline__ U16 f2bf(float f) {
    union { float f; U32 u; } v; v.f = f;
    return (U16)((v.u + 0x7FFFu + ((v.u >> 16) & 1u)) >> 16);  // RNE
}
__device__ __forceinline__ float bf2f(U16 h) {
    union { U32 u; float f; } v; v.u = ((U32)h) << 16;
    return v.f;
}
__device__ __forceinline__ void splitbf(float x, U16& hi, U16& lo) {
    hi = f2bf(x);
    lo = f2bf(x - bf2f(hi));
}
__device__ __forceinline__ float sigmoidf_(float x) { return 1.f / (1.f + __expf(-x)); }

__device__ __forceinline__ void glds16(const void* g, void* l) {
    __builtin_amdgcn_global_load_lds(
        (const __attribute__((address_space(1))) void*)g,
        (__attribute__((address_space(3))) void*)l, 16, 0, 0);
}

// swizzled LDS offset: row stride 64 U16, k-group g XORed with row&7
#define SWZ(row, g) ((row) * 64 + ((((g) ^ ((row) & 7))) * 8))

// ---------------- setup: adjT + xT transposes, weight split, h init ----------------
__global__ __launch_bounds__(256) void k_setup(
    const float* __restrict__ adj, U16* __restrict__ adjT,
    const float* __restrict__ w, const float* __restrict__ wih, const float* __restrict__ whh,
    U16* __restrict__ wThi, U16* __restrict__ wTlo,
    U16* __restrict__ wihhi, U16* __restrict__ wihlo,
    U16* __restrict__ whhhi, U16* __restrict__ whhlo,
    const float* __restrict__ x, U16* __restrict__ hhi, U16* __restrict__ hlo,
    U16* __restrict__ hThi, U16* __restrict__ hTlo)
{
    __shared__ float t[64 * 65];
    const int bid = blockIdx.x, tid = threadIdx.x;
    if (bid < 8192) {                              // adj fp32 [b][j][n] -> adjT bf16 [b][n][j]
        const int b = bid >> 8, rem = bid & 255;
        const int j0 = (rem & 15) * 64, n0 = (rem >> 4) * 64;
        const int rr = tid >> 4, c4 = (tid & 15) * 4;
#pragma unroll
        for (int p = 0; p < 4; ++p) {
            int j = p * 16 + rr;
            f32x4 v = *(const f32x4*)&adj[((size_t)b << 20) + ((size_t)(j0 + j) << 10) + n0 + c4];
#pragma unroll
            for (int u = 0; u < 4; ++u) t[j * 65 + c4 + u] = v[u];
        }
        __syncthreads();
#pragma unroll
        for (int p = 0; p < 4; ++p) {
            int n = p * 16 + rr;
            U16 h0 = f2bf(t[(c4 + 0) * 65 + n]);
            U16 h1 = f2bf(t[(c4 + 1) * 65 + n]);
            U16 h2 = f2bf(t[(c4 + 2) * 65 + n]);
            U16 h3 = f2bf(t[(c4 + 3) * 65 + n]);
            u32x2 pk; pk[0] = (U32)h0 | ((U32)h1 << 16); pk[1] = (U32)h2 | ((U32)h3 << 16);
            *(u32x2*)&adjT[((size_t)b << 20) + ((size_t)(n0 + n) << 10) + j0 + c4] = pk;
        }
    } else if (bid < 9216) {                       // x fp32 [b][j][c] -> hT split [b][c][j]
        const int bid2 = bid - 8192;               // 0..1023
        const int b = bid2 >> 5, rem = bid2 & 31;
        const int j0 = (rem & 15) * 64, c0 = (rem >> 4) * 64;
        const int rr = tid >> 4, c4 = (tid & 15) * 4;
#pragma unroll
        for (int p = 0; p < 4; ++p) {
            int j = p * 16 + rr;
            f32x4 v = *(const f32x4*)&x[(size_t)(b * 1024 + j0 + j) * 128 + c0 + c4];
#pragma unroll
            for (int u = 0; u < 4; ++u) t[j * 65 + c4 + u] = v[u];
        }
        __syncthreads();
#pragma unroll
        for (int p = 0; p < 4; ++p) {
            int cl = p * 16 + rr;                  // local c
            U16 hi0, lo0, hi1, lo1, hi2, lo2, hi3, lo3;
            splitbf(t[(c4 + 0) * 65 + cl], hi0, lo0);
            splitbf(t[(c4 + 1) * 65 + cl], hi1, lo1);
            splitbf(t[(c4 + 2) * 65 + cl], hi2, lo2);
            splitbf(t[(c4 + 3) * 65 + cl], hi3, lo3);
            size_t o = (((size_t)(b * 128 + c0 + cl)) << 10) + j0 + c4;
            u32x2 ph; ph[0] = (U32)hi0 | ((U32)hi1 << 16); ph[1] = (U32)hi2 | ((U32)hi3 << 16);
            u32x2 pl; pl[0] = (U32)lo0 | ((U32)lo1 << 16); pl[1] = (U32)lo2 | ((U32)lo3 << 16);
            *(u32x2*)&hThi[o] = ph;
            *(u32x2*)&hTlo[o] = pl;
        }
    } else if (bid < 11008) {                      // weight split (458752 elements)
        int i = (bid - 9216) * 256 + tid;
        if (i < 65536) {                           // weight [L][C][C] -> wT [L][d][c]
            int l = i >> 14, rem = i & 16383, c = rem >> 7, d = rem & 127;
            U16 hi, lo; splitbf(w[i], hi, lo);
            int o = (l << 14) + (d << 7) + c;
            wThi[o] = hi; wTlo[o] = lo;
        } else if (i < 262144) {
            int j = i - 65536;
            U16 hi, lo; splitbf(wih[j], hi, lo);
            wihhi[j] = hi; wihlo[j] = lo;
        } else {
            int j = i - 262144;
            U16 hi, lo; splitbf(whh[j], hi, lo);
            whhhi[j] = hi; whhlo[j] = lo;
        }
    } else {                                       // h init from x (4.19M elements)
        int base = (bid - 11008) * 2048 + tid;
#pragma unroll
        for (int p = 0; p < 8; ++p) {
            int i = base + p * 256;
            U16 hi, lo; splitbf(x[i], hi, lo);
            hhi[i] = hi; hlo[i] = lo;
        }
    }
}

// ---------------- k_mega8: q=adjT@hT -> m=qW -> gates -> GRU -> h,hT ----------------
__global__ __launch_bounds__(256, 2) void k_mega8(
    const U16* __restrict__ adjT,                                 // [NB][NN][NN]
    const U16* __restrict__ hTinhi, const U16* __restrict__ hTinlo, // [NB][128][1024] (prev dispatch)
    U16* __restrict__ hTouthi, U16* __restrict__ hToutlo,         // next-layer hT (unused if last)
    U16* hhi, U16* hlo,                                           // [MTOT][128] in-place (own rows)
    const U16* __restrict__ wtlhi, const U16* __restrict__ wtllo, // wT layer slice [128][128]
    const U16* __restrict__ wihhi, const U16* __restrict__ wihlo, // [384][128] layer slice
    const U16* __restrict__ whhhi, const U16* __restrict__ whhlo,
    const float* __restrict__ bih, const float* __restrict__ bhh, // [384] layer slice
    const float* __restrict__ mask,
    float* __restrict__ out, int last)
{
    __shared__ union {
        struct { U16 As[2][64 * 64]; U16 Bh[2][128 * 64]; U16 Bl[2][128 * 64]; } st; // 81920 B
        struct { U16 Mhi[64 * MP]; U16 Mlo[64 * MP];                                 // 34816 B
                 char pad[40960 - 64 * MP * 4];
                 float bounce[64 * 129]; } m;                                        // bounce at 40960
    } u;
    const int tid = threadIdx.x;
    const int lane = tid & 63, wv = tid >> 6;
    const int wd0 = wv * 32;                       // wave's 32-col slice
    const int lm = lane & 15, lk8 = (lane >> 4) * 8, quad = lane >> 4;
    const int xcd = blockIdx.x & 7;
    const int j = blockIdx.x >> 3;                 // 0..63
    const int bt = xcd * 4 + (j >> 4);
    const int n0 = (j & 15) * 64;
    const int row0 = bt * NN + n0;

    // ---- phase 1: q = adjT @ hT (2-product), dbuf glds pipeline, XOR swizzle ----
#define STAGE(kc, b)                                                                     \
    {                                                                                    \
        _Pragma("unroll")                                                                \
        for (int t = 0; t < 2; ++t) {                                                    \
            int li = tid + t * 256; int r = li >> 3, sg = li & 7;                        \
            glds16(&adjT[((size_t)bt << 20) + ((size_t)(n0 + r) << 10) + (kc)            \
                         + ((sg ^ (r & 7)) * 8)],                                        \
                   &u.st.As[b][li * 8]);                                                 \
        }                                                                                \
        _Pragma("unroll")                                                                \
        for (int t = 0; t < 4; ++t) {                                                    \
            int li = tid + t * 256; int d = li >> 3, sg = li & 7;                        \
            size_t o = (((size_t)(bt * 128 + d)) << 10) + (kc) + ((sg ^ (d & 7)) * 8);   \
            glds16(&hTinhi[o], &u.st.Bh[b][li * 8]);                                     \
            glds16(&hTinlo[o], &u.st.Bl[b][li * 8]);                                     \
        }                                                                                \
    }

    f32x4 qacc[4][2] = {};
    STAGE(0, 0);                                   // prologue
    for (int c = 0; c < 16; ++c) {
        const int b = c & 1;
        __syncthreads();                           // buf b ready
        if (c + 1 < 16) STAGE((c + 1) * 64, b ^ 1);
#pragma unroll
        for (int ks = 0; ks < 2; ++ks) {
            const int g = ks * 4 + quad;
            s16x8 a[4], bh[2], bl[2];
#pragma unroll
            for (int q = 0; q < 4; ++q)
                a[q] = *(const s16x8*)&u.st.As[b][SWZ(q * 16 + lm, g)];
#pragma unroll
            for (int q = 0; q < 2; ++q) {
                bh[q] = *(const s16x8*)&u.st.Bh[b][SWZ(wd0 + q * 16 + lm, g)];
                bl[q] = *(const s16x8*)&u.st.Bl[b][SWZ(wd0 + q * 16 + lm, g)];
            }
#pragma unroll
            for (int rt = 0; rt < 4; ++rt)
#pragma unroll
                for (int ct = 0; ct < 2; ++ct) {
                    f32x4 cc = qacc[rt][ct];
                    cc = __builtin_amdgcn_mfma_f32_16x16x32_bf16(a[rt], bh[ct], cc, 0, 0, 0);
                    cc = __builtin_amdgcn_mfma_f32_16x16x32_bf16(a[rt], bl[ct], cc, 0, 0, 0);
                    qacc[rt][ct] = cc;
                }
        }
    }
#undef STAGE
    __syncthreads();                               // all waves done reading staging LDS

    // ---- q -> LDS hi/lo ----
#pragma unroll
    for (int rt = 0; rt < 4; ++rt)
#pragma unroll
        for (int ct = 0; ct < 2; ++ct)
#pragma unroll
            for (int rr = 0; rr < 4; ++rr) {
                int rloc = rt * 16 + quad * 4 + rr;
                int d = wd0 + ct * 16 + lm;
                U16 hi, lo; splitbf(qacc[rt][ct][rr], hi, lo);
                u.m.Mhi[rloc * MP + d] = hi;
                u.m.Mlo[rloc * MP + d] = lo;
            }
    __syncthreads();                               // q visible block-wide

    // ---- phase 1.5: m = q @ W (3-product; a from LDS q, b from global wT) ----
    f32x4 macc[4][2] = {};
#pragma unroll
    for (int ks = 0; ks < 4; ++ks) {
        const int ko = ks * 32 + lk8;              // c-dim 0..127
        s16x8 qhi[4], qlo[4];
#pragma unroll
        for (int q = 0; q < 4; ++q) {
            qhi[q] = *(const s16x8*)&u.m.Mhi[(q * 16 + lm) * MP + ko];
            qlo[q] = *(const s16x8*)&u.m.Mlo[(q * 16 + lm) * MP + ko];
        }
#pragma unroll
        for (int ct = 0; ct < 2; ++ct) {
            const int col = wd0 + ct * 16 + lm;
            s16x8 whi = *(const s16x8*)&wtlhi[col * 128 + ko];
            s16x8 wlo = *(const s16x8*)&wtllo[col * 128 + ko];
#pragma unroll
            for (int rt = 0; rt < 4; ++rt) {
                f32x4 cc = macc[rt][ct];
                cc = __builtin_amdgcn_mfma_f32_16x16x32_bf16(qhi[rt], whi, cc, 0, 0, 0);
                cc = __builtin_amdgcn_mfma_f32_16x16x32_bf16(qhi[rt], wlo, cc, 0, 0, 0);
                cc = __builtin_amdgcn_mfma_f32_16x16x32_bf16(qlo[rt], whi, cc, 0, 0, 0);
                macc[rt][ct] = cc;
            }
        }
    }
    __syncthreads();                               // q fully consumed by ALL waves

    // ---- m -> LDS hi/lo (overwrites q region) ----
#pragma unroll
    for (int rt = 0; rt < 4; ++rt)
#pragma unroll
        for (int ct = 0; ct < 2; ++ct)
#pragma unroll
            for (int rr = 0; rr < 4; ++rr) {
                int rloc = rt * 16 + quad * 4 + rr;
                int d = wd0 + ct * 16 + lm;
                U16 hi, lo; splitbf(macc[rt][ct][rr], hi, lo);
                u.m.Mhi[rloc * MP + d] = hi;
                u.m.Mlo[rloc * MP + d] = lo;
            }
    // no barrier yet — h-chunks first, barrier before m-chunks

    // ---- phase 2: gates (K=256 concat [m|h], 3-product) + GRU ----
    f32x4 aR[4][2], aZ[4][2], aXN[4][2], aHN[4][2];
#pragma unroll
    for (int ct = 0; ct < 2; ++ct) {
        const int col = wd0 + ct * 16 + lm;
        const float bR  = bih[col]       + bhh[col];
        const float bZ  = bih[128 + col] + bhh[128 + col];
        const float bXN = bih[256 + col];
        const float bHN = bhh[256 + col];
#pragma unroll
        for (int rt = 0; rt < 4; ++rt) {
            aR[rt][ct]  = f32x4{bR, bR, bR, bR};
            aZ[rt][ct]  = f32x4{bZ, bZ, bZ, bZ};
            aXN[rt][ct] = f32x4{bXN, bXN, bXN, bXN};
            aHN[rt][ct] = f32x4{bHN, bHN, bHN, bHN};
        }
    }

    for (int cc = 0; cc < 4; ++cc) {
        const int ch = (cc + 2) & 3;               // order: 2,3 (h, global) then 0,1 (m, LDS)
        if (cc == 2) __syncthreads();              // m ds_writes visible block-wide
        const U16* __restrict__ Whi = (ch < 2) ? wihhi : whhhi;
        const U16* __restrict__ Wlo = (ch < 2) ? wihlo : whhlo;
        const int kb = (ch & 1) * 64;
#pragma unroll
        for (int ks = 0; ks < 2; ++ks) {
            const int ko = kb + ks * 32 + lk8;
            s16x8 ahi[4], alo[4];
            if (ch < 2) {
#pragma unroll
                for (int q = 0; q < 4; ++q) {
                    ahi[q] = *(const s16x8*)&u.m.Mhi[(q * 16 + lm) * MP + ko];
                    alo[q] = *(const s16x8*)&u.m.Mlo[(q * 16 + lm) * MP + ko];
                }
            } else {
#pragma unroll
                for (int q = 0; q < 4; ++q) {
                    size_t ao = (size_t)(row0 + q * 16 + lm) * 128 + ko;
                    ahi[q] = *(const s16x8*)&hhi[ao];
                    alo[q] = *(const s16x8*)&hlo[ao];
                }
            }
#pragma unroll
            for (int ct = 0; ct < 2; ++ct) {
                const int col = wd0 + ct * 16 + lm;
                s16x8 bhiR = *(const s16x8*)&Whi[(size_t)col * 128 + ko];
                s16x8 bloR = *(const s16x8*)&Wlo[(size_t)col * 128 + ko];
                s16x8 bhiZ = *(const s16x8*)&Whi[(size_t)(128 + col) * 128 + ko];
                s16x8 bloZ = *(const s16x8*)&Wlo[(size_t)(128 + col) * 128 + ko];
                s16x8 bhiN = *(const s16x8*)&Whi[(size_t)(256 + col) * 128 + ko];
                s16x8 bloN = *(const s16x8*)&Wlo[(size_t)(256 + col) * 128 + ko];
#pragma unroll
                for (int rt = 0; rt < 4; ++rt) {
                    f32x4 r = aR[rt][ct];
                    r = __builtin_amdgcn_mfma_f32_16x16x32_bf16(ahi[rt], bhiR, r, 0, 0, 0);
                    r = __builtin_amdgcn_mfma_f32_16x16x32_bf16(ahi[rt], bloR, r, 0, 0, 0);
                    r = __builtin_amdgcn_mfma_f32_16x16x32_bf16(alo[rt], bhiR, r, 0, 0, 0);
                    aR[rt][ct] = r;
                    f32x4 z = aZ[rt][ct];
                    z = __builtin_amdgcn_mfma_f32_16x16x32_bf16(ahi[rt], bhiZ, z, 0, 0, 0);
                    z = __builtin_amdgcn_mfma_f32_16x16x32_bf16(ahi[rt], bloZ, z, 0, 0, 0);
                    z = __builtin_amdgcn_mfma_f32_16x16x32_bf16(alo[rt], bhiZ, z, 0, 0, 0);
                    aZ[rt][ct] = z;
                }
                if (ch < 2) {
#pragma unroll
                    for (int rt = 0; rt < 4; ++rt) {
                        f32x4 n = aXN[rt][ct];
                        n = __builtin_amdgcn_mfma_f32_16x16x32_bf16(ahi[rt], bhiN, n, 0, 0, 0);
                        n = __builtin_amdgcn_mfma_f32_16x16x32_bf16(ahi[rt], bloN, n, 0, 0, 0);
                        n = __builtin_amdgcn_mfma_f32_16x16x32_bf16(alo[rt], bhiN, n, 0, 0, 0);
                        aXN[rt][ct] = n;
                    }
                } else {
#pragma unroll
                    for (int rt = 0; rt < 4; ++rt) {
                        f32x4 n = aHN[rt][ct];
                        n = __builtin_amdgcn_mfma_f32_16x16x32_bf16(ahi[rt], bhiN, n, 0, 0, 0);
                        n = __builtin_amdgcn_mfma_f32_16x16x32_bf16(ahi[rt], bloN, n, 0, 0, 0);
                        n = __builtin_amdgcn_mfma_f32_16x16x32_bf16(alo[rt], bhiN, n, 0, 0, 0);
                        aHN[rt][ct] = n;
                    }
                }
            }
        }
    }

    // ---- GRU epilogue; h in-place; hnew also to bounce (disjoint LDS) for hT ----
#pragma unroll
    for (int rt = 0; rt < 4; ++rt) {
#pragma unroll
        for (int ct = 0; ct < 2; ++ct) {
            const int col = wd0 + ct * 16 + lm;
#pragma unroll
            for (int rr = 0; rr < 4; ++rr) {
                const int rloc = rt * 16 + quad * 4 + rr;
                const int row = row0 + rloc;
                float r = sigmoidf_(aR[rt][ct][rr]);
                float z = sigmoidf_(aZ[rt][ct][rr]);
                float n = tanhf(aXN[rt][ct][rr] + r * aHN[rt][ct][rr]);
                size_t ho = (size_t)row * 128 + col;
                float hv = bf2f(hhi[ho]) + bf2f(hlo[ho]);
                float hnew = (1.f - z) * n + z * hv;
                if (last) {
                    out[ho] = hnew * mask[row];
                } else {
                    U16 hi2, lo2; splitbf(hnew, hi2, lo2);
                    hhi[ho] = hi2;
                    hlo[ho] = lo2;
                    u.m.bounce[rloc * 129 + col] = hnew;
                }
            }
        }
    }
    if (!last) {
        __syncthreads();                           // bounce complete
#pragma unroll
        for (int t = 0; t < 16; ++t) {             // hT[b][c][j] packed stores (k_hw2 pattern)
            int i = tid + t * 256; int c = i >> 5, j2 = (i & 31) * 2;
            float x0 = u.m.bounce[j2 * 129 + c], x1 = u.m.bounce[(j2 + 1) * 129 + c];
            U16 h0, l0, h1, l1; splitbf(x0, h0, l0); splitbf(x1, h1, l1);
            size_t o = (((size_t)(bt * 128 + c)) << 10) + n0 + j2;
            *(U32*)&hTouthi[o] = (U32)h0 | ((U32)h1 << 16);
            *(U32*)&hToutlo[o] = (U32)l0 | ((U32)l1 << 16);
        }
    }
}

// ---------------- launch ----------------
extern "C" void kernel_launch(void* const* d_in, const int* in_sizes, int n_in,
                              void* d_out, int out_size, void* d_ws, size_t ws_size,
                              hipStream_t stream) {
    (void)in_sizes; (void)n_in; (void)out_size; (void)ws_size;
    const float* x    = (const float*)d_in[0];
    const float* adj  = (const float*)d_in[1];
    const float* mask = (const float*)d_in[2];
    const float* wgt  = (const float*)d_in[3];
    const float* wih  = (const float*)d_in[4];
    const float* whh  = (const float*)d_in[5];
    const float* bih  = (const float*)d_in[6];
    const float* bhh  = (const float*)d_in[7];
    float* out = (float*)d_out;

    char* p = (char*)d_ws;
    U16* adjT    = (U16*)p;                p += (size_t)NB * NN * NN * 2;   // 67.1 MB
    U16* h_hi    = (U16*)p;                p += (size_t)MTOT * NC * 2;
    U16* h_lo    = (U16*)p;                p += (size_t)MTOT * NC * 2;
    U16* hTa_hi  = (U16*)p;                p += (size_t)NB * NC * NN * 2;
    U16* hTa_lo  = (U16*)p;                p += (size_t)NB * NC * NN * 2;
    U16* hTb_hi  = (U16*)p;                p += (size_t)NB * NC * NN * 2;
    U16* hTb_lo  = (U16*)p;                p += (size_t)NB * NC * NN * 2;
    U16* wT_hi   = (U16*)p;                p += (size_t)NL * NC * NC * 2;
    U16* wT_lo   = (U16*)p;                p += (size_t)NL * NC * NC * 2;
    U16* wih_hi  = (U16*)p;                p += (size_t)NL * 384 * NC * 2;
    U16* wih_lo  = (U16*)p;                p += (size_t)NL * 384 * NC * 2;
    U16* whh_hi  = (U16*)p;                p += (size_t)NL * 384 * NC * 2;
    U16* whh_lo  = (U16*)p;                p += (size_t)NL * 384 * NC * 2;

    k_setup<<<13056, 256, 0, stream>>>(adj, adjT, wgt, wih, whh,
                                       wT_hi, wT_lo, wih_hi, wih_lo, whh_hi, whh_lo,
                                       x, h_hi, h_lo, hTa_hi, hTa_lo);

    for (int l = 0; l < NL; ++l) {
        const U16* in_hi  = (l & 1) ? hTb_hi : hTa_hi;
        const U16* in_lo  = (l & 1) ? hTb_lo : hTa_lo;
        U16* out_hi       = (l & 1) ? hTa_hi : hTb_hi;
        U16* out_lo       = (l & 1) ? hTa_lo : hTb_lo;
        k_mega8<<<512, 256, 0, stream>>>(adjT, in_hi, in_lo, out_hi, out_lo,
                                         h_hi, h_lo,
                                         wT_hi + l * 16384, wT_lo + l * 16384,
                                         wih_hi + l * 49152, wih_lo + l * 49152,
                                         whh_hi + l * 49152, whh_lo + l * 49152,
                                         bih + l * 384, bhh + l * 384, mask,
                                         out, (l == NL - 1) ? 1 : 0);
    }
}